// Round 14
// baseline (94.743 us; speedup 1.0000x reference)
//
#include <hip/hip_runtime.h>

// GPDGaussian: per-pixel 629x3 conv -> (m, S=R^T diag(s) R, s)
// r14: 4 ROWS PER THREAD. Diagnosis r5-r13: every wave issues all 561 cs
// ds_reads regardless of structure; with 17-34 thr/px a wave covers ~3.8 px
// -> ~150 LDS reads/px -> per-CU LDS pipe co-saturated with VALU (~40us each).
// Fix: thread = (px = t/9, u = t%9) owns rows 4u..4u+3 (two f32x2). 9 thr/px
// -> 7.1 px/wave -> cs reads/px halved; VALU ops/px unchanged.
// Phase C: 2 rounds, threads remapped to 7 px x 17 row-pairs (all busy).

#define CCH 34
#define ACH 561
#define HWPIX 4096
#define NPIX 16384
#define PXB 14                  // pixels per block
#define TPP 9                   // threads per pixel (phase B)
#define NTHR 128                // 126 active in B
#define CSPX (141 * 8)          // cs bytes per px per chunk = 1128
#define VROW 36                 // V pair-row stride in dwords (144B)
#define VPX (17 * VROW * 4)     // 2448 B per-pixel V region
#define OFF_S 557056
#define OFF_s 19496960
#define LOG2E 1.4426950408889634f

typedef float    f32x2 __attribute__((ext_vector_type(2)));
typedef _Float16 h2    __attribute__((ext_vector_type(2)));

struct PairsT {
    short i[ACH]; short j[ACH];
    constexpr PairsT() : i(), j() {
        int p = 0;
        for (int a = 0; a < CCH - 1; ++a)
            for (int b = a + 1; b < CCH; ++b) { i[p] = (short)a; j[p] = (short)b; ++p; }
    }
};
__device__ constexpr PairsT PR{};

__device__ __forceinline__ float dot2h(h2 a, h2 b, float c) {
#if __has_builtin(__builtin_amdgcn_fdot2)
    return __builtin_amdgcn_fdot2(a, b, c, false);
#else
    return fmaf((float)a[0], (float)b[0], fmaf((float)a[1], (float)b[1], c));
#endif
}

// Givens rotation on two packed row-pairs (4 rows): 8 pk ops per rotation
__device__ __forceinline__ void rot4(f32x2& Rai, f32x2& Raj,
                                     f32x2& Rbi, f32x2& Rbj,
                                     f32x2 c2, f32x2 s2) {
    f32x2 ta = s2 * Rai;                 // old Rai
    f32x2 tb = s2 * Rbi;
    Rai = __builtin_elementwise_fma(c2, Rai, s2 * Raj);
    Rbi = __builtin_elementwise_fma(c2, Rbi, s2 * Rbj);
    Raj = __builtin_elementwise_fma(c2, Raj, -ta);
    Rbj = __builtin_elementwise_fma(c2, Rbj, -tb);
}

template <int P0, int P1>
__device__ __forceinline__ void apply_rots(f32x2* Ra, f32x2* Rb, const char* csb) {
    #pragma unroll
    for (int k = P0; k < P1; ++k) {
        f32x2 cell = *(const f32x2*)(csb + (k - P0) * 8);   // {c,s} b64 read
        f32x2 c2 = __builtin_shufflevector(cell, cell, 0, 0);
        f32x2 s2 = __builtin_shufflevector(cell, cell, 1, 1);
        rot4(Ra[PR.i[k]], Ra[PR.j[k]], Rb[PR.i[k]], Rb[PR.j[k]], c2, s2);
    }
}

__device__ __forceinline__ float2 cs_of(float wv) {
    // angle = pi*tanh(wv); HW cos/sin take revolutions: tanh(wv)/2
    float e  = __builtin_amdgcn_exp2f((2.0f * LOG2E) * wv);
    float tt = 1.0f - 2.0f * __builtin_amdgcn_rcpf(e + 1.0f);
    float rv = 0.5f * tt;
    return make_float2(__builtin_amdgcn_cosf(rv), __builtin_amdgcn_sinf(rv));
}

// one task = one pixel's angle l -> 8B {c,s} write
template <int G0, int LEN>
__device__ __forceinline__ void fill_cs(const float* __restrict__ Wm,
                                        const float* __restrict__ bvec,
                                        const float* xs, char* csbuf,
                                        int npx, int t) {
    for (int o = t; o < npx * LEN; o += NTHR) {
        int px = (int)((unsigned)o / (unsigned)LEN);
        int l  = o - px * LEN;
        int ch = 2 * CCH + G0 + l;
        float wv = fmaf(Wm[ch*3+0], xs[px*3+0],
                   fmaf(Wm[ch*3+1], xs[px*3+1], Wm[ch*3+2] * xs[px*3+2])) + bvec[ch];
        *(float2*)(csbuf + px * CSPX + l * 8) = cs_of(wv);
    }
}

__global__ __launch_bounds__(NTHR, 2) void gpd_kernel(
    const float* __restrict__ x,     // (4,3,64,64)
    const float* __restrict__ Wm,    // (629,3)
    const float* __restrict__ bvec,  // (629,)
    float* __restrict__ out)
{
    __shared__ alignas(16) char vbuf[7 * VPX];     // 17136 B (cs 15792 overlays)
    __shared__ _Float16 lds_sh[PXB * CCH];         // s in f16
    __shared__ float xs[PXB * 3];

    const int t   = threadIdx.x;
    const int p0  = blockIdx.x * PXB;
    const int npx = min(PXB, NPIX - p0);

    // ---- stage x into LDS ----
    for (int i = t; i < npx * 3; i += NTHR) {
        int px = (int)((unsigned)i / 3u); int c = i - px * 3;
        int p = p0 + px; int b = p >> 12; int hw = p & 4095;
        xs[i] = x[(b * 3 + c) * HWPIX + hw];
    }
    __syncthreads();

    // ---- A: mean + s channels ----
    for (int o = t; o < npx * 68; o += NTHR) {
        int q = (int)((unsigned)o / 68u); int ch = o - q * 68;
        int p = p0 + q; int b = p >> 12; int hw = p & 4095;
        float wv = fmaf(Wm[ch*3+0], xs[q*3+0],
                   fmaf(Wm[ch*3+1], xs[q*3+1], Wm[ch*3+2] * xs[q*3+2])) + bvec[ch];
        if (ch < CCH) {
            out[(size_t)p * CCH + ch] = wv;                       // mean
        } else {
            float e  = __builtin_amdgcn_exp2f(-wv * LOG2E);
            float sg = __builtin_amdgcn_rcpf(1.0f + e);
            float sv = fmaf(999.999f, sg, 0.001f);                // s
            int c = ch - CCH;
            out[OFF_s + (size_t)(b * CCH + c) * HWPIX + hw] = sv;
            lds_sh[q * CCH + c] = (_Float16)sv;
        }
    }

    const int px = t / TPP;                  // pixel owned (phase B), 0..13
    const int u  = t - px * TPP;             // row-quad index: rows 4u..4u+3
    const bool act = (t < PXB * TPP) && (px < npx);
    const char* csb = vbuf + px * CSPX;

    // Ra = rows (4u, 4u+1), Rb = rows (4u+2, 4u+3); u=8 -> Rb rows 34,35 are
    // pad: init 0, rotations keep them 0, never stored.
    f32x2 Ra[CCH], Rb[CCH];
    #pragma unroll
    for (int n = 0; n < CCH; ++n) {
        Ra[n][0] = (n == 4 * u)     ? 1.0f : 0.0f;
        Ra[n][1] = (n == 4 * u + 1) ? 1.0f : 0.0f;
        Rb[n][0] = (n == 4 * u + 2) ? 1.0f : 0.0f;
        Rb[n][1] = (n == 4 * u + 3) ? 1.0f : 0.0f;
    }

    // ---- 4 chunks: fill cos/sin -> rotate (single buffer, barriered) ----
    fill_cs<0, 141>(Wm, bvec, xs, vbuf, npx, t);
    __syncthreads();
    if (act) apply_rots<0, 141>(Ra, Rb, csb);
    __syncthreads();
    fill_cs<141, 140>(Wm, bvec, xs, vbuf, npx, t);
    __syncthreads();
    if (act) apply_rots<141, 281>(Ra, Rb, csb);
    __syncthreads();
    fill_cs<281, 140>(Wm, bvec, xs, vbuf, npx, t);
    __syncthreads();
    if (act) apply_rots<281, 421>(Ra, Rb, csb);
    __syncthreads();
    fill_cs<421, 140>(Wm, bvec, xs, vbuf, npx, t);
    __syncthreads();
    if (act) apply_rots<421, 561>(Ra, Rb, csb);
    __syncthreads();                         // all cs reads done; V overlays

    // ---- pack to f16 pair-row dwords; Ra/Rb die ----
    unsigned RhA[CCH], RhB[CCH];
    #pragma unroll
    for (int n = 0; n < CCH; ++n) {
        RhA[n] = __builtin_bit_cast(unsigned,
                     __builtin_amdgcn_cvt_pkrtz(Ra[n][0], Ra[n][1]));
        RhB[n] = __builtin_bit_cast(unsigned,
                     __builtin_amdgcn_cvt_pkrtz(Rb[n][0], Rb[n][1]));
    }

    // ---- phase C: 2 rounds of 7 px; write V then compute with remapped
    //      threads (7 px x 17 row-pairs, all 126 threads busy) ----
    const int cpx = t / 18;                  // compute-phase pixel 0..6
    const int u2  = t - cpx * 18;            // row-pair 0..17 (17 idle)

    #pragma unroll
    for (int h = 0; h < 2; ++h) {
        const int lr = px - 7 * h;           // this thread's V region if 0..6
        if (act && lr >= 0 && lr < 7) {
            unsigned* vbw = (unsigned*)(vbuf + lr * VPX);
            #pragma unroll
            for (int n = 0; n < CCH; ++n) vbw[(2*u)*VROW + n] = RhA[n];
            if (u < 8) {
                #pragma unroll
                for (int n = 0; n < CCH; ++n) vbw[(2*u+1)*VROW + n] = RhB[n];
            }
        }
        __syncthreads();

        const int gpx = 7 * h + cpx;
        if (t < 126 && u2 < 17 && gpx < npx) {
            const unsigned* vb = (const unsigned*)(vbuf + cpx * VPX);
            const _Float16* shp = lds_sh + gpx * CCH;
            float aL[CCH], aH[CCH];
            #pragma unroll
            for (int n = 0; n < CCH; ++n) { aL[n] = 0.0f; aH[n] = 0.0f; }
            for (int w = 0; w < 17; ++w) {
                const unsigned* row = vb + w * VROW;
                h2 sh2 = *(const h2*)(shp + 2 * w);
                h2 vkL = __builtin_bit_cast(h2, row[2 * u2])     * sh2;
                h2 vkH = __builtin_bit_cast(h2, row[2 * u2 + 1]) * sh2;
                #pragma unroll
                for (int g = 0; g < 8; ++g) {
                    uint4 rr = *(const uint4*)(row + 4 * g);
                    h2 r0 = __builtin_bit_cast(h2, rr.x), r1 = __builtin_bit_cast(h2, rr.y);
                    h2 r2 = __builtin_bit_cast(h2, rr.z), r3 = __builtin_bit_cast(h2, rr.w);
                    aL[4*g+0] = dot2h(vkL, r0, aL[4*g+0]);  aH[4*g+0] = dot2h(vkH, r0, aH[4*g+0]);
                    aL[4*g+1] = dot2h(vkL, r1, aL[4*g+1]);  aH[4*g+1] = dot2h(vkH, r1, aH[4*g+1]);
                    aL[4*g+2] = dot2h(vkL, r2, aL[4*g+2]);  aH[4*g+2] = dot2h(vkH, r2, aH[4*g+2]);
                    aL[4*g+3] = dot2h(vkL, r3, aL[4*g+3]);  aH[4*g+3] = dot2h(vkH, r3, aH[4*g+3]);
                }
                uint2 rr2 = *(const uint2*)(row + 32);
                h2 r32 = __builtin_bit_cast(h2, rr2.x), r33 = __builtin_bit_cast(h2, rr2.y);
                aL[32] = dot2h(vkL, r32, aL[32]);  aH[32] = dot2h(vkH, r32, aH[32]);
                aL[33] = dot2h(vkL, r33, aL[33]);  aH[33] = dot2h(vkH, r33, aH[33]);
            }
            // S rows 2u2, 2u2+1 = 68 contiguous floats = 17 aligned float4
            float* os = out + OFF_S + (size_t)(p0 + gpx) * (CCH * CCH) + 2 * u2 * CCH;
            #pragma unroll
            for (int q = 0; q < 17; ++q) {
                float4 v;
                v.x = (4*q+0 < 34) ? aL[4*q+0] : aH[4*q+0-34];
                v.y = (4*q+1 < 34) ? aL[4*q+1] : aH[4*q+1-34];
                v.z = (4*q+2 < 34) ? aL[4*q+2] : aH[4*q+2-34];
                v.w = (4*q+3 < 34) ? aL[4*q+3] : aH[4*q+3-34];
                *(float4*)(os + 4 * q) = v;
            }
        }
        __syncthreads();        // V regions reused by round 2
    }
}

extern "C" void kernel_launch(void* const* d_in, const int* in_sizes, int n_in,
                              void* d_out, int out_size, void* d_ws, size_t ws_size,
                              hipStream_t stream) {
    const float* x  = (const float*)d_in[0];
    const float* W  = (const float*)d_in[1];
    const float* bv = (const float*)d_in[2];
    float* out = (float*)d_out;
    const int nblk = (NPIX + PXB - 1) / PXB;   // 1171
    hipLaunchKernelGGL(gpd_kernel, dim3(nblk), dim3(NTHR), 0, stream,
                       x, W, bv, out);
}

// Round 15
// 88.628 us; speedup vs baseline: 1.0690x; 1.0690x over previous
//
#include <hip/hip_runtime.h>

// GPDGaussian: per-pixel 629x3 conv -> (m, S=R^T diag(s) R, s)
// r15 TWO INDEPENDENT ROTATION CHAINS PER THREAD (ILP=2).
// Diagnosis r5-r14: phase B is a 561-deep serial FMA chain; 1 chain/thread x
// ~2 waves/SIMD -> VALU issue every ~4cyc -> busy pinned at 50%, dur at 84us.
// Thread (g=t/17, u=t%17) owns rows (2u,2u+1) of pixels 2g AND 2g+1 as
// SEPARATE f32x2 sets RA/RB; interleaved rotations dual-issue in each other's
// latency shadow. cs cell {cA,cB,sA,sB}: 1 b128 read feeds both chains.

#define CCH 34
#define ACH 561
#define HWPIX 4096
#define NPIX 16384
#define PXB 14                  // pixels per block (7 pairs)
#define NTHR 128                // 119 active in B/C
#define CSPR (141 * 16)         // cs bytes per PAIR per chunk = 2256
#define VROW 36                 // V pair-row stride in dwords (144B)
#define VPX (17 * VROW * 4)     // 2448 B per-pixel V region
#define OFF_S 557056
#define OFF_s 19496960
#define LOG2E 1.4426950408889634f

typedef float    f32x2 __attribute__((ext_vector_type(2)));
typedef _Float16 h2    __attribute__((ext_vector_type(2)));

struct PairsT {
    short i[ACH]; short j[ACH];
    constexpr PairsT() : i(), j() {
        int p = 0;
        for (int a = 0; a < CCH - 1; ++a)
            for (int b = a + 1; b < CCH; ++b) { i[p] = (short)a; j[p] = (short)b; ++p; }
    }
};
__device__ constexpr PairsT PR{};

__device__ __forceinline__ float dot2h(h2 a, h2 b, float c) {
#if __has_builtin(__builtin_amdgcn_fdot2)
    return __builtin_amdgcn_fdot2(a, b, c, false);
#else
    return fmaf((float)a[0], (float)b[0], fmaf((float)a[1], (float)b[1], c));
#endif
}

// two interleaved Givens chains; A and B are data-independent
template <int P0, int P1>
__device__ __forceinline__ void apply_rots2(f32x2* RA, f32x2* RB, const char* csb) {
    #pragma unroll
    for (int k = P0; k < P1; ++k) {
        float4 cell = *(const float4*)(csb + (size_t)(k - P0) * 16); // {cA,cB,sA,sB}
        f32x2 cA; cA[0] = cell.x; cA[1] = cell.x;
        f32x2 sA; sA[0] = cell.z; sA[1] = cell.z;
        f32x2 cB; cB[0] = cell.y; cB[1] = cell.y;
        f32x2 sB; sB[0] = cell.w; sB[1] = cell.w;
        const int i = PR.i[k], j = PR.j[k];
        f32x2 tA = sA * RA[i];
        f32x2 tB = sB * RB[i];
        RA[i] = __builtin_elementwise_fma(cA, RA[i], sA * RA[j]);
        RB[i] = __builtin_elementwise_fma(cB, RB[i], sB * RB[j]);
        RA[j] = __builtin_elementwise_fma(cA, RA[j], -tA);
        RB[j] = __builtin_elementwise_fma(cB, RB[j], -tB);
    }
}

__device__ __forceinline__ float2 cs_of(float wv) {
    // angle = pi*tanh(wv); HW cos/sin take revolutions: tanh(wv)/2
    float e  = __builtin_amdgcn_exp2f((2.0f * LOG2E) * wv);
    float tt = 1.0f - 2.0f * __builtin_amdgcn_rcpf(e + 1.0f);
    float rv = 0.5f * tt;
    return make_float2(__builtin_amdgcn_cosf(rv), __builtin_amdgcn_sinf(rv));
}

// one task = one PAIR's angle l -> 16B {cA,cB,sA,sB} write
template <int G0, int LEN>
__device__ __forceinline__ void fill_cs(const float* __restrict__ Wm,
                                        const float* __restrict__ bvec,
                                        const float* xs, char* buf,
                                        int npr, int t) {
    for (int o = t; o < npr * LEN; o += NTHR) {
        int pr = (int)((unsigned)o / (unsigned)LEN);
        int l  = o - pr * LEN;
        int ch = 2 * CCH + G0 + l;
        float w0 = Wm[ch*3+0], w1 = Wm[ch*3+1], w2 = Wm[ch*3+2];
        float bb = bvec[ch];
        int pa = 2 * pr, pb = 2 * pr + 1;       // npx always even
        float2 A = cs_of(fmaf(w0, xs[pa*3+0], fmaf(w1, xs[pa*3+1], w2*xs[pa*3+2])) + bb);
        float2 B = cs_of(fmaf(w0, xs[pb*3+0], fmaf(w1, xs[pb*3+1], w2*xs[pb*3+2])) + bb);
        float4 cell; cell.x = A.x; cell.y = B.x; cell.z = A.y; cell.w = B.y;
        *(float4*)(buf + pr * CSPR + l * 16) = cell;
    }
}

__global__ __launch_bounds__(NTHR)
__attribute__((amdgpu_waves_per_eu(2, 3)))   // 170-reg budget: fits ~155 peak, no spill-chasing
void gpd_kernel(
    const float* __restrict__ x,     // (4,3,64,64)
    const float* __restrict__ Wm,    // (629,3)
    const float* __restrict__ bvec,  // (629,)
    float* __restrict__ out)
{
    __shared__ alignas(16) char vbuf[7 * VPX];     // 17136 B (cs 15792 overlays)
    __shared__ _Float16 lds_sh[PXB * CCH];         // s in f16
    __shared__ float xs[PXB * 3];

    const int t   = threadIdx.x;
    const int p0  = blockIdx.x * PXB;
    const int npx = min(PXB, NPIX - p0);           // always even
    const int npr = npx >> 1;

    // ---- stage x into LDS ----
    for (int i = t; i < npx * 3; i += NTHR) {
        int px = (int)((unsigned)i / 3u); int c = i - px * 3;
        int p = p0 + px; int b = p >> 12; int hw = p & 4095;
        xs[i] = x[(b * 3 + c) * HWPIX + hw];
    }
    __syncthreads();

    // ---- A: mean + s channels ----
    for (int o = t; o < npx * 68; o += NTHR) {
        int q = (int)((unsigned)o / 68u); int ch = o - q * 68;
        int p = p0 + q; int b = p >> 12; int hw = p & 4095;
        float wv = fmaf(Wm[ch*3+0], xs[q*3+0],
                   fmaf(Wm[ch*3+1], xs[q*3+1], Wm[ch*3+2] * xs[q*3+2])) + bvec[ch];
        if (ch < CCH) {
            out[(size_t)p * CCH + ch] = wv;                       // mean
        } else {
            float e  = __builtin_amdgcn_exp2f(-wv * LOG2E);
            float sg = __builtin_amdgcn_rcpf(1.0f + e);
            float sv = fmaf(999.999f, sg, 0.001f);                // s
            int c = ch - CCH;
            out[OFF_s + (size_t)(b * CCH + c) * HWPIX + hw] = sv;
            lds_sh[q * CCH + c] = (_Float16)sv;
        }
    }

    const int g = t / 17;                    // pair owned (0..6)
    const int u = t - g * 17;                // row-pair: rows (2u, 2u+1)
    const bool act = (t < 119) && (g < npr);
    const char* csb = vbuf + g * CSPR;

    // RA = rows (2u,2u+1) of px 2g; RB = same rows of px 2g+1 (indep chains)
    f32x2 RA[CCH], RB[CCH];
    #pragma unroll
    for (int n = 0; n < CCH; ++n) {
        float lo = (n == 2 * u) ? 1.0f : 0.0f;
        float hi = (n == 2 * u + 1) ? 1.0f : 0.0f;
        RA[n][0] = lo; RA[n][1] = hi;
        RB[n][0] = lo; RB[n][1] = hi;
    }

    // ---- 4 chunks: fill cos/sin -> rotate both chains ----
    fill_cs<0, 141>(Wm, bvec, xs, vbuf, npr, t);
    __syncthreads();
    __builtin_amdgcn_sched_barrier(0);
    if (act) apply_rots2<0, 141>(RA, RB, csb);
    __builtin_amdgcn_sched_barrier(0);
    __syncthreads();
    fill_cs<141, 140>(Wm, bvec, xs, vbuf, npr, t);
    __syncthreads();
    __builtin_amdgcn_sched_barrier(0);
    if (act) apply_rots2<141, 281>(RA, RB, csb);
    __builtin_amdgcn_sched_barrier(0);
    __syncthreads();
    fill_cs<281, 140>(Wm, bvec, xs, vbuf, npr, t);
    __syncthreads();
    __builtin_amdgcn_sched_barrier(0);
    if (act) apply_rots2<281, 421>(RA, RB, csb);
    __builtin_amdgcn_sched_barrier(0);
    __syncthreads();
    fill_cs<421, 140>(Wm, bvec, xs, vbuf, npr, t);
    __syncthreads();
    __builtin_amdgcn_sched_barrier(0);
    if (act) apply_rots2<421, 561>(RA, RB, csb);
    __builtin_amdgcn_sched_barrier(0);
    __syncthreads();                         // all cs reads done; V overlays

    // ---- pack both pixels' rows to f16 pair-row dwords; RA/RB die ----
    unsigned RhA[CCH], RhB[CCH];
    #pragma unroll
    for (int n = 0; n < CCH; ++n) {
        RhA[n] = __builtin_bit_cast(unsigned,
                     __builtin_amdgcn_cvt_pkrtz(RA[n][0], RA[n][1]));
        RhB[n] = __builtin_bit_cast(unsigned,
                     __builtin_amdgcn_cvt_pkrtz(RB[n][0], RB[n][1]));
    }

    // ---- phase C: round h computes px 2g+h (V region g), r13-proven code ----
    #pragma unroll
    for (int h = 0; h < 2; ++h) {
        if (act) {
            unsigned* vbw = (unsigned*)(vbuf + g * VPX);
            #pragma unroll
            for (int n = 0; n < CCH; ++n)
                vbw[u * VROW + n] = h ? RhB[n] : RhA[n];   // h is compile-time
        }
        __syncthreads();

        if (act) {
            const int gpx = 2 * g + h;
            const unsigned* vb = (const unsigned*)(vbuf + g * VPX);
            const _Float16* shp = lds_sh + gpx * CCH;
            float aL[CCH], aH[CCH];
            #pragma unroll
            for (int n = 0; n < CCH; ++n) { aL[n] = 0.0f; aH[n] = 0.0f; }
            for (int w = 0; w < 17; ++w) {
                const unsigned* row = vb + w * VROW;
                h2 sh2 = *(const h2*)(shp + 2 * w);
                h2 vkL = __builtin_bit_cast(h2, row[2 * u])     * sh2;
                h2 vkH = __builtin_bit_cast(h2, row[2 * u + 1]) * sh2;
                #pragma unroll
                for (int gg = 0; gg < 8; ++gg) {
                    uint4 rr = *(const uint4*)(row + 4 * gg);
                    h2 r0 = __builtin_bit_cast(h2, rr.x), r1 = __builtin_bit_cast(h2, rr.y);
                    h2 r2 = __builtin_bit_cast(h2, rr.z), r3 = __builtin_bit_cast(h2, rr.w);
                    aL[4*gg+0] = dot2h(vkL, r0, aL[4*gg+0]);  aH[4*gg+0] = dot2h(vkH, r0, aH[4*gg+0]);
                    aL[4*gg+1] = dot2h(vkL, r1, aL[4*gg+1]);  aH[4*gg+1] = dot2h(vkH, r1, aH[4*gg+1]);
                    aL[4*gg+2] = dot2h(vkL, r2, aL[4*gg+2]);  aH[4*gg+2] = dot2h(vkH, r2, aH[4*gg+2]);
                    aL[4*gg+3] = dot2h(vkL, r3, aL[4*gg+3]);  aH[4*gg+3] = dot2h(vkH, r3, aH[4*gg+3]);
                }
                uint2 rr2 = *(const uint2*)(row + 32);
                h2 r32 = __builtin_bit_cast(h2, rr2.x), r33 = __builtin_bit_cast(h2, rr2.y);
                aL[32] = dot2h(vkL, r32, aL[32]);  aH[32] = dot2h(vkH, r32, aH[32]);
                aL[33] = dot2h(vkL, r33, aL[33]);  aH[33] = dot2h(vkH, r33, aH[33]);
            }
            // S rows 2u, 2u+1 = 68 contiguous floats = 17 aligned float4
            float* os = out + OFF_S + (size_t)(p0 + gpx) * (CCH * CCH) + 2 * u * CCH;
            #pragma unroll
            for (int q = 0; q < 17; ++q) {
                float4 v;
                v.x = (4*q+0 < 34) ? aL[4*q+0] : aH[4*q+0-34];
                v.y = (4*q+1 < 34) ? aL[4*q+1] : aH[4*q+1-34];
                v.z = (4*q+2 < 34) ? aL[4*q+2] : aH[4*q+2-34];
                v.w = (4*q+3 < 34) ? aL[4*q+3] : aH[4*q+3-34];
                *(float4*)(os + 4 * q) = v;
            }
        }
        __syncthreads();        // V regions reused by round 2
    }
}

extern "C" void kernel_launch(void* const* d_in, const int* in_sizes, int n_in,
                              void* d_out, int out_size, void* d_ws, size_t ws_size,
                              hipStream_t stream) {
    const float* x  = (const float*)d_in[0];
    const float* W  = (const float*)d_in[1];
    const float* bv = (const float*)d_in[2];
    float* out = (float*)d_out;
    const int nblk = (NPIX + PXB - 1) / PXB;   // 1171
    hipLaunchKernelGGL(gpd_kernel, dim3(nblk), dim3(NTHR), 0, stream,
                       x, W, bv, out);
}

// Round 16
// 81.161 us; speedup vs baseline: 1.1673x; 1.0920x over previous
//
#include <hip/hip_runtime.h>

// GPDGaussian: per-pixel 629x3 conv -> (m, S=R^T diag(s) R, s)
// r16 = r13 per-px structure at FULL residency: 256 thr / 15 px per block
// (255/256 = 99.6% lane packing), LDS 37.9KB -> exactly 4 blocks/CU = 16
// waves/CU; grid 1093 blocks = 4.27/CU supply. All three caps align at 4.
// (r5-r15: every variant left residency at ~2 waves/SIMD via LDS, grid
// supply, or register collapse -> latency/barrier stalls pinned dur at 84us.)

#define CCH 34
#define ACH 561
#define HWPIX 4096
#define NPIX 16384
#define PXB 15                  // pixels per block
#define TPP 17                  // threads per pixel
#define NTHR 256                // 255 active in B/C
#define CSPX (141 * 8)          // cs bytes per px per chunk = 1128
#define VROW 36                 // V pair-row stride in dwords (144B)
#define VPX (17 * VROW * 4)     // 2448 B per-pixel V region
#define OFF_S 557056
#define OFF_s 19496960
#define LOG2E 1.4426950408889634f

typedef float    f32x2 __attribute__((ext_vector_type(2)));
typedef _Float16 h2    __attribute__((ext_vector_type(2)));

struct PairsT {
    short i[ACH]; short j[ACH];
    constexpr PairsT() : i(), j() {
        int p = 0;
        for (int a = 0; a < CCH - 1; ++a)
            for (int b = a + 1; b < CCH; ++b) { i[p] = (short)a; j[p] = (short)b; ++p; }
    }
};
__device__ constexpr PairsT PR{};

__device__ __forceinline__ float dot2h(h2 a, h2 b, float c) {
#if __has_builtin(__builtin_amdgcn_fdot2)
    return __builtin_amdgcn_fdot2(a, b, c, false);
#else
    return fmaf((float)a[0], (float)b[0], fmaf((float)a[1], (float)b[1], c));
#endif
}

// Givens rotation on packed row-pair: Ri' = c*Ri + s*Rj ; Rj' = c*Rj - s*Ri
__device__ __forceinline__ void rot2(f32x2& Ri, f32x2& Rj, f32x2 c2, f32x2 s2) {
    f32x2 t1 = s2 * Rj;
    f32x2 t2 = s2 * Ri;
    Ri = __builtin_elementwise_fma(c2, Ri, t1);
    Rj = __builtin_elementwise_fma(c2, Rj, -t2);
}

template <int P0, int P1>
__device__ __forceinline__ void apply_rots(f32x2* R2, const char* csb) {
    #pragma unroll
    for (int k = P0; k < P1; ++k) {
        f32x2 cell = *(const f32x2*)(csb + (k - P0) * 8);   // {c,s} b64 read
        f32x2 c2 = __builtin_shufflevector(cell, cell, 0, 0);
        f32x2 s2 = __builtin_shufflevector(cell, cell, 1, 1);
        rot2(R2[PR.i[k]], R2[PR.j[k]], c2, s2);
    }
}

__device__ __forceinline__ float2 cs_of(float wv) {
    // angle = pi*tanh(wv); HW cos/sin take revolutions: tanh(wv)/2
    float e  = __builtin_amdgcn_exp2f((2.0f * LOG2E) * wv);
    float tt = 1.0f - 2.0f * __builtin_amdgcn_rcpf(e + 1.0f);
    float rv = 0.5f * tt;
    return make_float2(__builtin_amdgcn_cosf(rv), __builtin_amdgcn_sinf(rv));
}

// one task = one pixel's angle l -> 8B {c,s} write
template <int G0, int LEN>
__device__ __forceinline__ void fill_cs(const float* __restrict__ Wm,
                                        const float* __restrict__ bvec,
                                        const float* xs, char* csbuf,
                                        int npx, int t) {
    for (int o = t; o < npx * LEN; o += NTHR) {
        int px = (int)((unsigned)o / (unsigned)LEN);
        int l  = o - px * LEN;
        int ch = 2 * CCH + G0 + l;
        float wv = fmaf(Wm[ch*3+0], xs[px*3+0],
                   fmaf(Wm[ch*3+1], xs[px*3+1], Wm[ch*3+2] * xs[px*3+2])) + bvec[ch];
        *(float2*)(csbuf + px * CSPX + l * 8) = cs_of(wv);
    }
}

__global__ __launch_bounds__(NTHR, 4) void gpd_kernel(
    const float* __restrict__ x,     // (4,3,64,64)
    const float* __restrict__ Wm,    // (629,3)
    const float* __restrict__ bvec,  // (629,)
    float* __restrict__ out)
{
    __shared__ alignas(16) char vbuf[PXB * VPX];   // 36720 B (cs 16920 overlays)
    __shared__ _Float16 lds_sh[PXB * CCH];         // s in f16 (1020 B)
    __shared__ float xs[PXB * 3];                  // 180 B

    const int t   = threadIdx.x;
    const int p0  = blockIdx.x * PXB;
    const int npx = min(PXB, NPIX - p0);

    // ---- stage x into LDS ----
    for (int i = t; i < npx * 3; i += NTHR) {
        int px = (int)((unsigned)i / 3u); int c = i - px * 3;
        int p = p0 + px; int b = p >> 12; int hw = p & 4095;
        xs[i] = x[(b * 3 + c) * HWPIX + hw];
    }
    __syncthreads();

    // ---- A: mean + s channels ----
    for (int o = t; o < npx * 68; o += NTHR) {
        int q = (int)((unsigned)o / 68u); int ch = o - q * 68;
        int p = p0 + q; int b = p >> 12; int hw = p & 4095;
        float wv = fmaf(Wm[ch*3+0], xs[q*3+0],
                   fmaf(Wm[ch*3+1], xs[q*3+1], Wm[ch*3+2] * xs[q*3+2])) + bvec[ch];
        if (ch < CCH) {
            out[(size_t)p * CCH + ch] = wv;                       // mean
        } else {
            float e  = __builtin_amdgcn_exp2f(-wv * LOG2E);
            float sg = __builtin_amdgcn_rcpf(1.0f + e);
            float sv = fmaf(999.999f, sg, 0.001f);                // s
            int c = ch - CCH;
            out[OFF_s + (size_t)(b * CCH + c) * HWPIX + hw] = sv;
            lds_sh[q * CCH + c] = (_Float16)sv;
        }
    }

    const int px = t / TPP;                  // pixel owned (0..14; t=255 -> 15)
    const int u  = t - px * TPP;             // row-pair index: rows (2u, 2u+1)
    const bool act = (px < npx) && (px < PXB);
    const char* csb = vbuf + px * CSPX;

    f32x2 R2[CCH];                           // R2[n] = {R[2u][n], R[2u+1][n]}
    #pragma unroll
    for (int n = 0; n < CCH; ++n) {
        R2[n][0] = (n == 2 * u)     ? 1.0f : 0.0f;
        R2[n][1] = (n == 2 * u + 1) ? 1.0f : 0.0f;
    }

    // ---- 4 chunks: fill cos/sin -> rotate ----
    fill_cs<0, 141>(Wm, bvec, xs, vbuf, npx, t);
    __syncthreads();
    if (act) apply_rots<0, 141>(R2, csb);
    __syncthreads();
    fill_cs<141, 140>(Wm, bvec, xs, vbuf, npx, t);
    __syncthreads();
    if (act) apply_rots<141, 281>(R2, csb);
    __syncthreads();
    fill_cs<281, 140>(Wm, bvec, xs, vbuf, npx, t);
    __syncthreads();
    if (act) apply_rots<281, 421>(R2, csb);
    __syncthreads();
    fill_cs<421, 140>(Wm, bvec, xs, vbuf, npx, t);
    __syncthreads();
    if (act) apply_rots<421, 561>(R2, csb);
    __syncthreads();                         // all cs reads done; V overlays

    // ---- V write: cvt_pkrtz(R2[n]) IS the f16 row-pair dword [u][n] ----
    if (act) {
        unsigned* vb = (unsigned*)(vbuf + px * VPX) + u * VROW;
        #pragma unroll
        for (int n = 0; n < CCH; ++n)
            vb[n] = __builtin_bit_cast(unsigned,
                        __builtin_amdgcn_cvt_pkrtz(R2[n][0], R2[n][1]));
    }
    __syncthreads();

    // ---- phase C: S rows 2u and 2u+1 in ONE pass (shared rr reads) ----
    if (act) {
        const unsigned* vb = (const unsigned*)(vbuf + px * VPX);
        const _Float16* sh = lds_sh + px * CCH;
        float aL[CCH], aH[CCH];
        #pragma unroll
        for (int n = 0; n < CCH; ++n) { aL[n] = 0.0f; aH[n] = 0.0f; }
        for (int mp = 0; mp < 17; ++mp) {
            const unsigned* row = vb + mp * VROW;
            h2 sh2 = *(const h2*)(sh + 2 * mp);
            h2 vkL = __builtin_bit_cast(h2, row[2 * u])     * sh2;
            h2 vkH = __builtin_bit_cast(h2, row[2 * u + 1]) * sh2;
            #pragma unroll
            for (int g = 0; g < 8; ++g) {
                uint4 rr = *(const uint4*)(row + 4 * g);
                h2 r0 = __builtin_bit_cast(h2, rr.x), r1 = __builtin_bit_cast(h2, rr.y);
                h2 r2 = __builtin_bit_cast(h2, rr.z), r3 = __builtin_bit_cast(h2, rr.w);
                aL[4*g+0] = dot2h(vkL, r0, aL[4*g+0]);  aH[4*g+0] = dot2h(vkH, r0, aH[4*g+0]);
                aL[4*g+1] = dot2h(vkL, r1, aL[4*g+1]);  aH[4*g+1] = dot2h(vkH, r1, aH[4*g+1]);
                aL[4*g+2] = dot2h(vkL, r2, aL[4*g+2]);  aH[4*g+2] = dot2h(vkH, r2, aH[4*g+2]);
                aL[4*g+3] = dot2h(vkL, r3, aL[4*g+3]);  aH[4*g+3] = dot2h(vkH, r3, aH[4*g+3]);
            }
            uint2 rr2 = *(const uint2*)(row + 32);
            h2 r32 = __builtin_bit_cast(h2, rr2.x), r33 = __builtin_bit_cast(h2, rr2.y);
            aL[32] = dot2h(vkL, r32, aL[32]);  aH[32] = dot2h(vkH, r32, aH[32]);
            aL[33] = dot2h(vkL, r33, aL[33]);  aH[33] = dot2h(vkH, r33, aH[33]);
        }
        // write rows 2u,2u+1 = 68 contiguous floats = 17 aligned float4
        float* os = out + OFF_S + (size_t)(p0 + px) * (CCH * CCH) + 2 * u * CCH;
        #pragma unroll
        for (int q = 0; q < 17; ++q) {
            float4 v;
            v.x = (4*q+0 < 34) ? aL[4*q+0] : aH[4*q+0-34];
            v.y = (4*q+1 < 34) ? aL[4*q+1] : aH[4*q+1-34];
            v.z = (4*q+2 < 34) ? aL[4*q+2] : aH[4*q+2-34];
            v.w = (4*q+3 < 34) ? aL[4*q+3] : aH[4*q+3-34];
            *(float4*)(os + 4 * q) = v;
        }
    }
}

extern "C" void kernel_launch(void* const* d_in, const int* in_sizes, int n_in,
                              void* d_out, int out_size, void* d_ws, size_t ws_size,
                              hipStream_t stream) {
    const float* x  = (const float*)d_in[0];
    const float* W  = (const float*)d_in[1];
    const float* bv = (const float*)d_in[2];
    float* out = (float*)d_out;
    const int nblk = (NPIX + PXB - 1) / PXB;   // 1093
    hipLaunchKernelGGL(gpd_kernel, dim3(nblk), dim3(NTHR), 0, stream,
                       x, W, bv, out);
}